// Round 9
// baseline (270.645 us; speedup 1.0000x reference)
//
#include <hip/hip_runtime.h>
#include <math.h>

// Net (per image b of 256):  x: (dh=256, wt=256), dh=d*16+h, wt=w*16+t
//  L1: w1 (17,17,9,9) pad4 -> (dh_o=64, wt=256) relu      [MFMA, 81 taps, K=256]
//  L2: w2 (7,7,7,7)  pad3 -> same, relu                   [MFMA, 49 taps, K=64]
//  L3: w3 (5,5,5,5)  pad2 -> relu
//  L4: w4 (3,3,3,3)  pad1 -> relu
//  L5: w5 (8,8)      -> sigmoid -> out (256,16,16)
//
// R17: tail LDS-layout round. R16 (266.2 best): conv 145 (VGPR 116, B-dbuf +
//  JIT-A), tail ~113 vs ~45 floor. The tail still uses the stride-72 layout
//  conv abandoned in R11 (measured there: 14.5M -> 3.9M conflicts, -10us).
//  Tail runs 83 taps of the same 8x ds_read_b128 pattern at HALF the
//  waves/CU -> conflicts hurt more. This round: stride-64 + XOR swizzle
//  (col ^ ((row&7)<<3)) on the UNCHANGED R8 flat tail structure (the clean,
//  unconfounded test R11 never ran). conv untouched.
//  Ledger: conv best 145 (R16), tail best ~100-113 (R8 structure 2-slice).

typedef short bf16x8 __attribute__((ext_vector_type(8)));
typedef float f32x4 __attribute__((ext_vector_type(4)));
typedef unsigned int u32x4 __attribute__((ext_vector_type(4)));

// conv_l1 tile geometry (padded + XOR-swizzled)
#define XTS 64    // row stride in shorts (128 B)
#define NROWS 396 // 16 w * 24 pt + 12-row zero block
#define ZROW 384  // zero block base row (0 mod 8!)

__device__ __forceinline__ int xts(int row, int col) {
  return row * XTS + (col ^ ((row & 7) << 3));
}

__device__ __forceinline__ unsigned short f2bf(float f) {
  unsigned int u = __float_as_uint(f);
  u += 0x7fffu + ((u >> 16) & 1u);  // RNE
  return (unsigned short)(u >> 16);
}

// ---------------- B-matrix precompute (layouts unchanged) --------------------
template <int KSZ, int PAD>
__device__ __forceinline__ void build_mid(const float* __restrict__ w,
                                          unsigned short* __restrict__ Bg, int gid) {
  const int lane = gid & 63;
  const int n_tile = (gid >> 6) & 3;
  const int chunk = (gid >> 8) & 1;
  const int tap = gid >> 9;
  const int kw = tap / KSZ, kt = tap - kw * KSZ;
  const int dh_o = n_tile * 16 + (lane & 15);
  const int d_o = dh_o >> 3, h_o = dh_o & 7;
  const int kbase = chunk * 32 + (lane >> 4) * 8;
  unsigned int pk[4];
#pragma unroll
  for (int p = 0; p < 4; ++p) {
    unsigned short half[2];
#pragma unroll
    for (int s = 0; s < 2; ++s) {
      const int k = kbase + p * 2 + s;
      const int d_i = k >> 3, h_i = k & 7;
      const int kd = d_i - d_o + PAD, kh = h_i - h_o + PAD;
      float v = 0.f;
      if (kd >= 0 && kd < KSZ && kh >= 0 && kh < KSZ)
        v = w[((kd * KSZ + kh) * KSZ + kw) * KSZ + kt];
      half[s] = f2bf(v);
    }
    pk[p] = (unsigned int)half[0] | ((unsigned int)half[1] << 16);
  }
  *(int4*)(Bg + (size_t)gid * 8) = make_int4(pk[0], pk[1], pk[2], pk[3]);
}

__global__ __launch_bounds__(256) void build_all(const float* __restrict__ w1,
                                                 const float* __restrict__ w2,
                                                 const float* __restrict__ w3,
                                                 const float* __restrict__ w4,
                                                 unsigned short* __restrict__ Bg1,
                                                 unsigned short* __restrict__ Bg2,
                                                 unsigned short* __restrict__ Bg3,
                                                 unsigned short* __restrict__ Bg4) {
  const int bid = blockIdx.x, tid = threadIdx.x;
  if (bid < 648) {  // L1: 81 taps * 8 chunks * 4 ntiles * 64 lanes
    const int gid = bid * 256 + tid;
    const int lane = gid & 63;
    const int n_tile = (gid >> 6) & 3;
    const int chunk = (gid >> 8) & 7;
    const int kwkt = gid >> 11;
    const int kw = kwkt / 9, kt = kwkt - kw * 9;
    const int dh_o = n_tile * 16 + (lane & 15);
    const int d_o = dh_o >> 3, h_o = dh_o & 7;
    const int kbase = chunk * 32 + (lane >> 4) * 8;
    unsigned int pk[4];
#pragma unroll
    for (int p = 0; p < 4; ++p) {
      unsigned short half[2];
#pragma unroll
      for (int s = 0; s < 2; ++s) {
        const int k = kbase + p * 2 + s;
        const int d_i = k >> 4, h_i = k & 15;
        const int kd = d_i - d_o + 4, kh = h_i - h_o + 4;
        float v = 0.f;
        if (kd >= 0 && kd < 17 && kh >= 0 && kh < 17)
          v = w1[((kd * 17 + kh) * 9 + kw) * 9 + kt];
        half[s] = f2bf(v);
      }
      pk[p] = (unsigned int)half[0] | ((unsigned int)half[1] << 16);
    }
    *(int4*)(Bg1 + (size_t)gid * 8) = make_int4(pk[0], pk[1], pk[2], pk[3]);
  } else if (bid < 746) {
    build_mid<7, 3>(w2, Bg2, (bid - 648) * 256 + tid);
  } else if (bid < 796) {
    build_mid<5, 2>(w3, Bg3, (bid - 746) * 256 + tid);
  } else {
    build_mid<3, 1>(w4, Bg4, (bid - 796) * 256 + tid);
  }
}

// ---------------- conv_l1 helpers (R16, unchanged) ---------------------------
__device__ __forceinline__ void l1_loadA(const unsigned short* XT, const int (&arb)[4],
                                         int kt, int tl, int quad, int chalf,
                                         bf16x8 (&A)[4]) {
  const int sw = ((tl + kt) & 7) << 3;
  const int c = (quad * 8 + chalf * 32) ^ sw;
  const int ko = kt * XTS;
#pragma unroll
  for (int m = 0; m < 4; ++m)
    A[m] = *(const bf16x8*)&XT[arb[m] + ko + c];
}

__device__ __forceinline__ void l1_loadB(const unsigned short* __restrict__ Bt, int kt,
                                         bf16x8 (&B)[8]) {
#pragma unroll
  for (int c = 0; c < 2; ++c)
#pragma unroll
    for (int n = 0; n < 4; ++n)
      B[c * 4 + n] = *(const bf16x8*)(Bt + (size_t)kt * 16384 + c * 2048 + n * 512);
}

__device__ __forceinline__ void mfma_half(const bf16x8 (&A)[4], const bf16x8* B,
                                          f32x4 (&acc)[4][4]) {
  __builtin_amdgcn_s_setprio(1);  // T5: measured +15% (R13)
#pragma unroll
  for (int m = 0; m < 4; ++m)
#pragma unroll
    for (int n = 0; n < 4; ++n)
      acc[m][n] = __builtin_amdgcn_mfma_f32_16x16x32_bf16(A[m], B[n], acc[m][n], 0, 0, 0);
  __builtin_amdgcn_s_setprio(0);
}

// ---------------- conv_l1: grid 512 = image x khalf, fp32 partials (2 slices)
__global__ __launch_bounds__(256) void conv_l1_mfma(const float* __restrict__ x,
                                                    const unsigned short* __restrict__ Bg,
                                                    float* __restrict__ P) {
  __shared__ __align__(16) unsigned short XT[NROWS * XTS];  // 50688 B
  const int bx = blockIdx.x;
  const int b = bx >> 1, khalf = bx & 1;
  const int tid = threadIdx.x;
  const int lane = tid & 63, wave = tid >> 6;
  const int quad = lane >> 4, tl = lane & 15;
  const float* xb = x + (size_t)b * 65536;
  f32x4 acc[4][4] = {};

  // zero the whole padded tile once (pads + zero block stay 0 across qq)
  for (int j = tid; j < (NROWS * XTS) / 8; j += 256)
    *(int4*)&XT[j * 8] = make_int4(0, 0, 0, 0);
  __syncthreads();

  for (int qq = 0; qq < 2; ++qq) {
    const int q = khalf * 2 + qq;  // dh-quarter
    if (qq) __syncthreads();       // all reads of previous quarter done
    // stage quarter q: row r = w*24 + t + 4, col k (dh_local), swizzled
#pragma unroll
    for (int it = 0; it < 8; ++it) {
      const int i = tid + it * 256;
      const int dhp = i >> 6, wtq = i & 63;
      const int r0 = (wtq >> 2) * 24 + (wtq & 3) * 4 + 4;
      const float4 ra = *(const float4*)(xb + (size_t)(q * 64 + 2 * dhp) * 256 + wtq * 4);
      const float4 rb =
          *(const float4*)(xb + (size_t)(q * 64 + 2 * dhp + 1) * 256 + wtq * 4);
      const float a0[4] = {ra.x, ra.y, ra.z, ra.w};
      const float a1[4] = {rb.x, rb.y, rb.z, rb.w};
#pragma unroll
      for (int j = 0; j < 4; ++j) {
        const unsigned int p = (unsigned int)f2bf(a0[j]) | ((unsigned int)f2bf(a1[j]) << 16);
        *(unsigned int*)&XT[xts(r0 + j, dhp * 2)] = p;
      }
    }
    __syncthreads();

    const unsigned short* Bt = Bg + (size_t)(q * 2) * 2048 + lane * 8;
    for (int kw = 0; kw < 9; ++kw) {
      // per-kw row-base products; invalid w -> zero-block row (reads zeros)
      int arb[4];
#pragma unroll
      for (int m = 0; m < 4; ++m) {
        const int w_i = wave * 4 + m + kw - 4;
        arb[m] = (((unsigned)w_i < 16u) ? (w_i * 24 + tl) : ZROW) * XTS;
      }
      // B double-buffered (L2 latency); A just-in-time per c-half (LDS).
      bf16x8 B0[8], B1[8];
      l1_loadB(Bt, 0, B0);
#pragma unroll
      for (int kt = 0; kt < 9; ++kt) {
        bf16x8* Bc = (kt & 1) ? B1 : B0;  // static under full unroll
        bf16x8* Bn = (kt & 1) ? B0 : B1;
        if (kt < 8) l1_loadB(Bt, kt + 1, *(bf16x8(*)[8])Bn);
        bf16x8 A[4];
        l1_loadA(XT, arb, kt, tl, quad, 0, A);
        mfma_half(A, Bc, acc);
        l1_loadA(XT, arb, kt, tl, quad, 1, A);
        mfma_half(A, Bc + 4, acc);
      }
      Bt += 9 * 16384;
    }
  }

  // store fp32 partial.  D: col=lane&15 (dh_o), row=quad*4+reg (wt)
  float* Pb = P + (size_t)(khalf * 256 + b) * 16384;
#pragma unroll
  for (int m = 0; m < 4; ++m)
#pragma unroll
    for (int n = 0; n < 4; ++n) {
      const int dh_o = n * 16 + tl;
      const int wt0 = wave * 64 + m * 16 + quad * 4;
      *(float4*)&Pb[(size_t)dh_o * 256 + wt0] = *(const float4*)&acc[m][n];
    }
}

// ---------------- fused tail: R8 flat structure + stride-64 XOR layout -------
// 512 thr = 8 waves in a 4(m) x 2(n) wave grid; m=4, n=2 tiles/wave.
// XT2: rows = wt (0..255) + zero row 256; 64 shorts/row; col ^ ((row&7)<<3).
#define T64 64

__device__ __forceinline__ int txs(int row, int col) {
  return row * T64 + (col ^ ((row & 7) << 3));
}

template <int KSZ, int PAD>
__device__ __forceinline__ void tail_load_tap(const unsigned short* XT,
                                              const unsigned short* __restrict__ Bg, int kwkt,
                                              int mw, int nh, int lane, int quad, int tl,
                                              bf16x8 (&A)[8], bf16x8 (&B)[4]) {
  const int kw = kwkt / KSZ, kt = kwkt - kw * KSZ;
  const int t_i = tl + kt - PAD;
  const bool tv = (unsigned)t_i < 16u;
  int ro[4];
#pragma unroll
  for (int m = 0; m < 4; ++m) {
    const int w_i = mw * 4 + m + kw - PAD;
    const bool v = tv && ((unsigned)w_i < 16u);
    const int row = v ? (w_i * 16 + t_i) : 256;  // row 256 = zeros
    ro[m] = row * T64 + ((quad * 8) ^ ((row & 7) << 3));
  }
  // second c-half = ^32 (single-bit col flip commutes with the XOR swizzle)
#pragma unroll
  for (int c = 0; c < 2; ++c)
#pragma unroll
    for (int m = 0; m < 4; ++m)
      A[c * 4 + m] = *(const bf16x8*)&XT[ro[m] ^ (c * 32)];
#pragma unroll
  for (int c = 0; c < 2; ++c)
#pragma unroll
    for (int n = 0; n < 2; ++n)
      B[c * 2 + n] =
          *(const bf16x8*)(Bg + (((size_t)(kwkt * 2 + c) * 4 + (nh * 2 + n)) << 9) + lane * 8);
}

__device__ __forceinline__ void mfma8(const bf16x8 (&A)[8], const bf16x8 (&B)[4],
                                      f32x4 (&acc)[4][2]) {
  __builtin_amdgcn_s_setprio(1);  // T5
#pragma unroll
  for (int c = 0; c < 2; ++c)
#pragma unroll
    for (int m = 0; m < 4; ++m)
#pragma unroll
      for (int n = 0; n < 2; ++n)
        acc[m][n] = __builtin_amdgcn_mfma_f32_16x16x32_bf16(A[c * 4 + m], B[c * 2 + n],
                                                            acc[m][n], 0, 0, 0);
  __builtin_amdgcn_s_setprio(0);
}

template <int KSZ, int PAD, int NT>
__device__ __forceinline__ void run_layer(unsigned short* XT,
                                          const unsigned short* __restrict__ Bg,
                                          const float bias, int mw, int nh, int lane,
                                          int quad, int tl) {
  f32x4 acc[4][2] = {};
  {
    bf16x8 A0[8], B0[4], A1[8], B1[4];
    tail_load_tap<KSZ, PAD>(XT, Bg, 0, mw, nh, lane, quad, tl, A0, B0);
    int k = 0;
    while (true) {
      if (k + 1 < NT) tail_load_tap<KSZ, PAD>(XT, Bg, k + 1, mw, nh, lane, quad, tl, A1, B1);
      mfma8(A0, B0, acc);
      if (++k >= NT) break;
      if (k + 1 < NT) tail_load_tap<KSZ, PAD>(XT, Bg, k + 1, mw, nh, lane, quad, tl, A0, B0);
      mfma8(A1, B1, acc);
      if (++k >= NT) break;
    }
  }
  __syncthreads();  // all XT reads for this layer complete
  // epilogue: bias+relu+bf16, re-transpose into XT[wt][dh] (swizzled)
#pragma unroll
  for (int m = 0; m < 4; ++m)
#pragma unroll
    for (int n = 0; n < 2; ++n) {
      const int col = (nh * 2 + n) * 16 + tl;
      const int wt0 = mw * 64 + m * 16 + quad * 4;
#pragma unroll
      for (int j = 0; j < 4; ++j)
        XT[txs(wt0 + j, col)] = f2bf(fmaxf(acc[m][n][j] + bias, 0.f));
    }
  __syncthreads();  // XT updated for next layer
}

__global__ __launch_bounds__(512) void tail_fused(const float* __restrict__ P,
                                                  const unsigned short* __restrict__ Bg2,
                                                  const unsigned short* __restrict__ Bg3,
                                                  const unsigned short* __restrict__ Bg4,
                                                  const float* __restrict__ b1,
                                                  const float* __restrict__ b2,
                                                  const float* __restrict__ b3,
                                                  const float* __restrict__ b4,
                                                  const float* __restrict__ w5,
                                                  const float* __restrict__ b5,
                                                  float* __restrict__ out) {
  __shared__ __align__(16) unsigned short XT[257 * T64];  // 32896 B
  const int b = blockIdx.x;
  const int tid = threadIdx.x;
  const int lane = tid & 63, wave = tid >> 6;
  const int quad = lane >> 4, tl = lane & 15;
  const int mw = wave >> 1, nh = wave & 1;
  const float* p0 = P + (size_t)b * 16384;
  const float* p1 = p0 + (size_t)256 * 16384;
  const float bias1 = b1[0];

  if (tid < 8) *(int4*)&XT[256 * T64 + tid * 8] = make_int4(0, 0, 0, 0);
  // stage: XT[wt][dh] = bf16(relu(P0 + P1 + b1)), swizzled
#pragma unroll
  for (int it = 0; it < 4; ++it) {
    const int i = tid + it * 512;
    const int dhp = i >> 6, wtq = i & 63;
    const size_t off0 = (size_t)(2 * dhp) * 256 + wtq * 4;
    const float4 r0a = *(const float4*)(p0 + off0);
    const float4 r0b = *(const float4*)(p1 + off0);
    const float4 r1a = *(const float4*)(p0 + off0 + 256);
    const float4 r1b = *(const float4*)(p1 + off0 + 256);
    float a0[4] = {r0a.x + r0b.x, r0a.y + r0b.y, r0a.z + r0b.z, r0a.w + r0b.w};
    float a1[4] = {r1a.x + r1b.x, r1a.y + r1b.y, r1a.z + r1b.z, r1a.w + r1b.w};
#pragma unroll
    for (int j = 0; j < 4; ++j) {
      const unsigned short lo = f2bf(fmaxf(a0[j] + bias1, 0.f));
      const unsigned short hi = f2bf(fmaxf(a1[j] + bias1, 0.f));
      const unsigned int p = (unsigned int)lo | ((unsigned int)hi << 16);
      *(unsigned int*)&XT[txs(wtq * 4 + j, dhp * 2)] = p;
    }
  }
  __syncthreads();

  run_layer<7, 3, 49>(XT, Bg2, b2[0], mw, nh, lane, quad, tl);
  run_layer<5, 2, 25>(XT, Bg3, b3[0], mw, nh, lane, quad, tl);
  run_layer<3, 1, 9>(XT, Bg4, b4[0], mw, nh, lane, quad, tl);

  // L5: out[wt] = sigmoid(b5 + sum_dh w5[dh] * y4[wt][dh]); XT rows are wt
  if (tid < 256) {
    const int wt = tid;
    float s = b5[0];
#pragma unroll
    for (int k8 = 0; k8 < 8; ++k8) {
      const u32x4 v = *(const u32x4*)&XT[txs(wt, k8 * 8)];
      const unsigned int uu[4] = {(unsigned int)v.x, (unsigned int)v.y, (unsigned int)v.z,
                                  (unsigned int)v.w};
#pragma unroll
      for (int p = 0; p < 4; ++p) {
        const float lo = __uint_as_float(uu[p] << 16);
        const float hi = __uint_as_float(uu[p] & 0xFFFF0000u);
        s += lo * w5[k8 * 8 + p * 2] + hi * w5[k8 * 8 + p * 2 + 1];
      }
    }
    out[(size_t)b * 256 + wt] = 1.f / (1.f + expf(-s));
  }
}

extern "C" void kernel_launch(void* const* d_in, const int* in_sizes, int n_in,
                              void* d_out, int out_size, void* d_ws, size_t ws_size,
                              hipStream_t stream) {
  const float* corr = (const float*)d_in[0];
  const float* w1 = (const float*)d_in[1];
  const float* b1 = (const float*)d_in[2];
  const float* w2 = (const float*)d_in[3];
  const float* b2 = (const float*)d_in[4];
  const float* w3 = (const float*)d_in[5];
  const float* b3 = (const float*)d_in[6];
  const float* w4 = (const float*)d_in[7];
  const float* b4 = (const float*)d_in[8];
  const float* w5 = (const float*)d_in[9];
  const float* b5 = (const float*)d_in[10];

  // ws: [0,32M) P khalf slices; [64M,..) B matrices
  float* P = (float*)d_ws;
  unsigned short* Bg1 = (unsigned short*)((char*)d_ws + (64u << 20));
  unsigned short* Bg2 = Bg1 + (size_t)81 * 8 * 4 * 64 * 8;
  unsigned short* Bg3 = Bg2 + (size_t)49 * 2 * 4 * 64 * 8;
  unsigned short* Bg4 = Bg3 + (size_t)25 * 2 * 4 * 64 * 8;

  build_all<<<814, 256, 0, stream>>>(w1, w2, w3, w4, Bg1, Bg2, Bg3, Bg4);
  conv_l1_mfma<<<512, 256, 0, stream>>>(corr, Bg1, P);
  tail_fused<<<256, 512, 0, stream>>>(P, Bg2, Bg3, Bg4, b1, b2, b3, b4, w5, b5,
                                      (float*)d_out);
}

// Round 10
// 257.737 us; speedup vs baseline: 1.0501x; 1.0501x over previous
//
#include <hip/hip_runtime.h>
#include <math.h>

// Net (per image b of 256):  x: (dh=256, wt=256), dh=d*16+h, wt=w*16+t
//  L1: w1 (17,17,9,9) pad4 -> (dh_o=64, wt=256) relu      [MFMA, 81 taps, K=256]
//  L2: w2 (7,7,7,7)  pad3 -> same, relu                   [MFMA, 49 taps, K=64]
//  L3: w3 (5,5,5,5)  pad2 -> relu
//  L4: w4 (3,3,3,3)  pad1 -> relu
//  L5: w5 (8,8)      -> sigmoid -> out (256,16,16)
//
// R18: tail A-rotation round. R17 lessons: (1) tail swizzle hurt (stride-72's
//  144B row stride is a natural 4-dword bank skew -> already 2-way/free;
//  conflicts 3.93M are conv's, constant R11-R17); (2) conv 138-145 is noise.
//  Tail is LDS-issue-bound: per tap/CU A-reads 768 cyc > MFMA 620 cyc.
//  Fix: A(kw+1,m)==A(kw,m+1) for fixed kt -> kt-outer/kw-inner loop with a
//  4-slot circular A window, slot (kw+m)&3 (compile-time, no movs): per kt
//  8 initial + 2/kw reads instead of 8/tap -> L2 layer 392->140 reads/wave.
//  Everything else = R16 (best, 266.2): conv verbatim, tail TTS=72 flat.

typedef short bf16x8 __attribute__((ext_vector_type(8)));
typedef float f32x4 __attribute__((ext_vector_type(4)));
typedef unsigned int u32x4 __attribute__((ext_vector_type(4)));

// conv_l1 tile geometry (padded + XOR-swizzled)
#define XTS 64    // row stride in shorts (128 B)
#define NROWS 396 // 16 w * 24 pt + 12-row zero block
#define ZROW 384  // zero block base row (0 mod 8!)
// tail tile geometry (R8/R16 structure)
#define TTS 72    // tail row stride in shorts (natural bank skew)

__device__ __forceinline__ int xts(int row, int col) {
  return row * XTS + (col ^ ((row & 7) << 3));
}

__device__ __forceinline__ unsigned short f2bf(float f) {
  unsigned int u = __float_as_uint(f);
  u += 0x7fffu + ((u >> 16) & 1u);  // RNE
  return (unsigned short)(u >> 16);
}

// ---------------- B-matrix precompute (layouts unchanged) --------------------
template <int KSZ, int PAD>
__device__ __forceinline__ void build_mid(const float* __restrict__ w,
                                          unsigned short* __restrict__ Bg, int gid) {
  const int lane = gid & 63;
  const int n_tile = (gid >> 6) & 3;
  const int chunk = (gid >> 8) & 1;
  const int tap = gid >> 9;
  const int kw = tap / KSZ, kt = tap - kw * KSZ;
  const int dh_o = n_tile * 16 + (lane & 15);
  const int d_o = dh_o >> 3, h_o = dh_o & 7;
  const int kbase = chunk * 32 + (lane >> 4) * 8;
  unsigned int pk[4];
#pragma unroll
  for (int p = 0; p < 4; ++p) {
    unsigned short half[2];
#pragma unroll
    for (int s = 0; s < 2; ++s) {
      const int k = kbase + p * 2 + s;
      const int d_i = k >> 3, h_i = k & 7;
      const int kd = d_i - d_o + PAD, kh = h_i - h_o + PAD;
      float v = 0.f;
      if (kd >= 0 && kd < KSZ && kh >= 0 && kh < KSZ)
        v = w[((kd * KSZ + kh) * KSZ + kw) * KSZ + kt];
      half[s] = f2bf(v);
    }
    pk[p] = (unsigned int)half[0] | ((unsigned int)half[1] << 16);
  }
  *(int4*)(Bg + (size_t)gid * 8) = make_int4(pk[0], pk[1], pk[2], pk[3]);
}

__global__ __launch_bounds__(256) void build_all(const float* __restrict__ w1,
                                                 const float* __restrict__ w2,
                                                 const float* __restrict__ w3,
                                                 const float* __restrict__ w4,
                                                 unsigned short* __restrict__ Bg1,
                                                 unsigned short* __restrict__ Bg2,
                                                 unsigned short* __restrict__ Bg3,
                                                 unsigned short* __restrict__ Bg4) {
  const int bid = blockIdx.x, tid = threadIdx.x;
  if (bid < 648) {  // L1: 81 taps * 8 chunks * 4 ntiles * 64 lanes
    const int gid = bid * 256 + tid;
    const int lane = gid & 63;
    const int n_tile = (gid >> 6) & 3;
    const int chunk = (gid >> 8) & 7;
    const int kwkt = gid >> 11;
    const int kw = kwkt / 9, kt = kwkt - kw * 9;
    const int dh_o = n_tile * 16 + (lane & 15);
    const int d_o = dh_o >> 3, h_o = dh_o & 7;
    const int kbase = chunk * 32 + (lane >> 4) * 8;
    unsigned int pk[4];
#pragma unroll
    for (int p = 0; p < 4; ++p) {
      unsigned short half[2];
#pragma unroll
      for (int s = 0; s < 2; ++s) {
        const int k = kbase + p * 2 + s;
        const int d_i = k >> 4, h_i = k & 15;
        const int kd = d_i - d_o + 4, kh = h_i - h_o + 4;
        float v = 0.f;
        if (kd >= 0 && kd < 17 && kh >= 0 && kh < 17)
          v = w1[((kd * 17 + kh) * 9 + kw) * 9 + kt];
        half[s] = f2bf(v);
      }
      pk[p] = (unsigned int)half[0] | ((unsigned int)half[1] << 16);
    }
    *(int4*)(Bg1 + (size_t)gid * 8) = make_int4(pk[0], pk[1], pk[2], pk[3]);
  } else if (bid < 746) {
    build_mid<7, 3>(w2, Bg2, (bid - 648) * 256 + tid);
  } else if (bid < 796) {
    build_mid<5, 2>(w3, Bg3, (bid - 746) * 256 + tid);
  } else {
    build_mid<3, 1>(w4, Bg4, (bid - 796) * 256 + tid);
  }
}

// ---------------- conv_l1 helpers (R16, unchanged) ---------------------------
__device__ __forceinline__ void l1_loadA(const unsigned short* XT, const int (&arb)[4],
                                         int kt, int tl, int quad, int chalf,
                                         bf16x8 (&A)[4]) {
  const int sw = ((tl + kt) & 7) << 3;
  const int c = (quad * 8 + chalf * 32) ^ sw;
  const int ko = kt * XTS;
#pragma unroll
  for (int m = 0; m < 4; ++m)
    A[m] = *(const bf16x8*)&XT[arb[m] + ko + c];
}

__device__ __forceinline__ void l1_loadB(const unsigned short* __restrict__ Bt, int kt,
                                         bf16x8 (&B)[8]) {
#pragma unroll
  for (int c = 0; c < 2; ++c)
#pragma unroll
    for (int n = 0; n < 4; ++n)
      B[c * 4 + n] = *(const bf16x8*)(Bt + (size_t)kt * 16384 + c * 2048 + n * 512);
}

__device__ __forceinline__ void mfma_half(const bf16x8 (&A)[4], const bf16x8* B,
                                          f32x4 (&acc)[4][4]) {
  __builtin_amdgcn_s_setprio(1);  // T5: measured +15% (R13)
#pragma unroll
  for (int m = 0; m < 4; ++m)
#pragma unroll
    for (int n = 0; n < 4; ++n)
      acc[m][n] = __builtin_amdgcn_mfma_f32_16x16x32_bf16(A[m], B[n], acc[m][n], 0, 0, 0);
  __builtin_amdgcn_s_setprio(0);
}

// ---------------- conv_l1: grid 512 = image x khalf, fp32 partials (2 slices)
__global__ __launch_bounds__(256) void conv_l1_mfma(const float* __restrict__ x,
                                                    const unsigned short* __restrict__ Bg,
                                                    float* __restrict__ P) {
  __shared__ __align__(16) unsigned short XT[NROWS * XTS];  // 50688 B
  const int bx = blockIdx.x;
  const int b = bx >> 1, khalf = bx & 1;
  const int tid = threadIdx.x;
  const int lane = tid & 63, wave = tid >> 6;
  const int quad = lane >> 4, tl = lane & 15;
  const float* xb = x + (size_t)b * 65536;
  f32x4 acc[4][4] = {};

  // zero the whole padded tile once (pads + zero block stay 0 across qq)
  for (int j = tid; j < (NROWS * XTS) / 8; j += 256)
    *(int4*)&XT[j * 8] = make_int4(0, 0, 0, 0);
  __syncthreads();

  for (int qq = 0; qq < 2; ++qq) {
    const int q = khalf * 2 + qq;  // dh-quarter
    if (qq) __syncthreads();       // all reads of previous quarter done
    // stage quarter q: row r = w*24 + t + 4, col k (dh_local), swizzled
#pragma unroll
    for (int it = 0; it < 8; ++it) {
      const int i = tid + it * 256;
      const int dhp = i >> 6, wtq = i & 63;
      const int r0 = (wtq >> 2) * 24 + (wtq & 3) * 4 + 4;
      const float4 ra = *(const float4*)(xb + (size_t)(q * 64 + 2 * dhp) * 256 + wtq * 4);
      const float4 rb =
          *(const float4*)(xb + (size_t)(q * 64 + 2 * dhp + 1) * 256 + wtq * 4);
      const float a0[4] = {ra.x, ra.y, ra.z, ra.w};
      const float a1[4] = {rb.x, rb.y, rb.z, rb.w};
#pragma unroll
      for (int j = 0; j < 4; ++j) {
        const unsigned int p = (unsigned int)f2bf(a0[j]) | ((unsigned int)f2bf(a1[j]) << 16);
        *(unsigned int*)&XT[xts(r0 + j, dhp * 2)] = p;
      }
    }
    __syncthreads();

    const unsigned short* Bt = Bg + (size_t)(q * 2) * 2048 + lane * 8;
    for (int kw = 0; kw < 9; ++kw) {
      // per-kw row-base products; invalid w -> zero-block row (reads zeros)
      int arb[4];
#pragma unroll
      for (int m = 0; m < 4; ++m) {
        const int w_i = wave * 4 + m + kw - 4;
        arb[m] = (((unsigned)w_i < 16u) ? (w_i * 24 + tl) : ZROW) * XTS;
      }
      // B double-buffered (L2 latency); A just-in-time per c-half (LDS).
      bf16x8 B0[8], B1[8];
      l1_loadB(Bt, 0, B0);
#pragma unroll
      for (int kt = 0; kt < 9; ++kt) {
        bf16x8* Bc = (kt & 1) ? B1 : B0;  // static under full unroll
        bf16x8* Bn = (kt & 1) ? B0 : B1;
        if (kt < 8) l1_loadB(Bt, kt + 1, *(bf16x8(*)[8])Bn);
        bf16x8 A[4];
        l1_loadA(XT, arb, kt, tl, quad, 0, A);
        mfma_half(A, Bc, acc);
        l1_loadA(XT, arb, kt, tl, quad, 1, A);
        mfma_half(A, Bc + 4, acc);
      }
      Bt += 9 * 16384;
    }
  }

  // store fp32 partial.  D: col=lane&15 (dh_o), row=quad*4+reg (wt)
  float* Pb = P + (size_t)(khalf * 256 + b) * 16384;
#pragma unroll
  for (int m = 0; m < 4; ++m)
#pragma unroll
    for (int n = 0; n < 4; ++n) {
      const int dh_o = n * 16 + tl;
      const int wt0 = wave * 64 + m * 16 + quad * 4;
      *(float4*)&Pb[(size_t)dh_o * 256 + wt0] = *(const float4*)&acc[m][n];
    }
}

// ---------------- fused tail: L2 -> L3 -> L4 -> L5 ---------------------------
// 512 thr = 8 waves (4 m-groups x 2 n-halves), m=4 n=2 tiles/wave, TTS=72.
// kt-outer / kw-inner with 4-slot circular A window: slot (kw+m)&3 is
// compile-time under full unroll (no register moves). A(kw+1,m)==A(kw,m+1).
template <int KSZ, int PAD>
__device__ __forceinline__ void run_layer(unsigned short* XT,
                                          const unsigned short* __restrict__ Bg,
                                          const float bias, int mw, int nh, int lane,
                                          int quad, int tl) {
  f32x4 acc[4][2] = {};
  const unsigned short* BgL = Bg + lane * 8;
#pragma unroll
  for (int kt = 0; kt < KSZ; ++kt) {
    const int t_i = tl + kt - PAD;
    const bool tv = (unsigned)t_i < 16u;
    bf16x8 Aw[2][4];  // [chalf][slot]
    // initial window (kw=0): logical m -> slot m
#pragma unroll
    for (int m = 0; m < 4; ++m) {
      const int w_i = mw * 4 + m - PAD;
      const int row = (tv && (unsigned)w_i < 16u) ? (w_i * 16 + t_i) : 256;
      const int ro = row * TTS + quad * 8;
      Aw[0][m] = *(const bf16x8*)&XT[ro];
      Aw[1][m] = *(const bf16x8*)&XT[ro + 32];
    }
    bf16x8 Bb[2][4];  // B double-buffer
#pragma unroll
    for (int c = 0; c < 2; ++c)
#pragma unroll
      for (int n = 0; n < 2; ++n)
        Bb[0][c * 2 + n] =
            *(const bf16x8*)(BgL + (((size_t)(kt * 2 + c) * 4 + (nh * 2 + n)) << 9));
#pragma unroll
    for (int kw = 0; kw < KSZ; ++kw) {
      const int cur = kw & 1, nxt = cur ^ 1;
      if (kw + 1 < KSZ) {  // prefetch next tap's B (L2 latency cover)
        const int kwkt = (kw + 1) * KSZ + kt;
#pragma unroll
        for (int c = 0; c < 2; ++c)
#pragma unroll
          for (int n = 0; n < 2; ++n)
            Bb[nxt][c * 2 + n] =
                *(const bf16x8*)(BgL + (((size_t)(kwkt * 2 + c) * 4 + (nh * 2 + n)) << 9));
      }
      __builtin_amdgcn_s_setprio(1);  // T5
#pragma unroll
      for (int c = 0; c < 2; ++c)
#pragma unroll
        for (int m = 0; m < 4; ++m)
#pragma unroll
          for (int n = 0; n < 2; ++n)
            acc[m][n] = __builtin_amdgcn_mfma_f32_16x16x32_bf16(
                Aw[c][(kw + m) & 3], Bb[cur][c * 2 + n], acc[m][n], 0, 0, 0);
      __builtin_amdgcn_s_setprio(0);
      if (kw + 1 < KSZ) {  // incoming A: logical m=3 at kw+1 -> slot kw&3
        const int w_i = mw * 4 + 4 + kw - PAD;
        const int row = (tv && (unsigned)w_i < 16u) ? (w_i * 16 + t_i) : 256;
        const int ro = row * TTS + quad * 8;
        Aw[0][kw & 3] = *(const bf16x8*)&XT[ro];
        Aw[1][kw & 3] = *(const bf16x8*)&XT[ro + 32];
      }
    }
  }
  __syncthreads();  // all XT reads for this layer complete
  // epilogue: bias+relu+bf16, re-transpose into XT[wt][dh]
#pragma unroll
  for (int m = 0; m < 4; ++m)
#pragma unroll
    for (int n = 0; n < 2; ++n) {
      const int col = (nh * 2 + n) * 16 + tl;
      const int wt0 = mw * 64 + m * 16 + quad * 4;
#pragma unroll
      for (int j = 0; j < 4; ++j)
        XT[(wt0 + j) * TTS + col] = f2bf(fmaxf(acc[m][n][j] + bias, 0.f));
    }
  __syncthreads();  // XT updated for next layer
}

__global__ __launch_bounds__(512) void tail_fused(const float* __restrict__ P,
                                                  const unsigned short* __restrict__ Bg2,
                                                  const unsigned short* __restrict__ Bg3,
                                                  const unsigned short* __restrict__ Bg4,
                                                  const float* __restrict__ b1,
                                                  const float* __restrict__ b2,
                                                  const float* __restrict__ b3,
                                                  const float* __restrict__ b4,
                                                  const float* __restrict__ w5,
                                                  const float* __restrict__ b5,
                                                  float* __restrict__ out) {
  __shared__ __align__(16) unsigned short XT[257 * TTS];  // 37 KB
  const int b = blockIdx.x;
  const int tid = threadIdx.x;
  const int lane = tid & 63, wave = tid >> 6;
  const int quad = lane >> 4, tl = lane & 15;
  const int mw = wave >> 1, nh = wave & 1;
  const float* p0 = P + (size_t)b * 16384;
  const float* p1 = p0 + (size_t)256 * 16384;
  const float bias1 = b1[0];

  if (tid < 9) *(int4*)&XT[256 * TTS + tid * 8] = make_int4(0, 0, 0, 0);
  // stage: XT[wt][dh] = bf16(relu(P0 + P1 + b1))
#pragma unroll
  for (int it = 0; it < 4; ++it) {
    const int i = tid + it * 512;
    const int dhp = i >> 6, wtq = i & 63;
    const size_t off0 = (size_t)(2 * dhp) * 256 + wtq * 4;
    const float4 r0a = *(const float4*)(p0 + off0);
    const float4 r0b = *(const float4*)(p1 + off0);
    const float4 r1a = *(const float4*)(p0 + off0 + 256);
    const float4 r1b = *(const float4*)(p1 + off0 + 256);
    float a0[4] = {r0a.x + r0b.x, r0a.y + r0b.y, r0a.z + r0b.z, r0a.w + r0b.w};
    float a1[4] = {r1a.x + r1b.x, r1a.y + r1b.y, r1a.z + r1b.z, r1a.w + r1b.w};
#pragma unroll
    for (int j = 0; j < 4; ++j) {
      const unsigned short lo = f2bf(fmaxf(a0[j] + bias1, 0.f));
      const unsigned short hi = f2bf(fmaxf(a1[j] + bias1, 0.f));
      const unsigned int p = (unsigned int)lo | ((unsigned int)hi << 16);
      *(unsigned int*)&XT[(wtq * 4 + j) * TTS + dhp * 2] = p;
    }
  }
  __syncthreads();

  run_layer<7, 3>(XT, Bg2, b2[0], mw, nh, lane, quad, tl);
  run_layer<5, 2>(XT, Bg3, b3[0], mw, nh, lane, quad, tl);
  run_layer<3, 1>(XT, Bg4, b4[0], mw, nh, lane, quad, tl);

  // L5: out[wt] = sigmoid(b5 + sum_dh w5[dh] * y4[wt][dh]); XT rows are wt
  if (tid < 256) {
    const int wt = tid;
    float s = b5[0];
    const unsigned short* row = &XT[wt * TTS];
#pragma unroll
    for (int k8 = 0; k8 < 8; ++k8) {
      const u32x4 v = *(const u32x4*)&row[k8 * 8];
      const unsigned int uu[4] = {(unsigned int)v.x, (unsigned int)v.y, (unsigned int)v.z,
                                  (unsigned int)v.w};
#pragma unroll
      for (int p = 0; p < 4; ++p) {
        const float lo = __uint_as_float(uu[p] << 16);
        const float hi = __uint_as_float(uu[p] & 0xFFFF0000u);
        s += lo * w5[k8 * 8 + p * 2] + hi * w5[k8 * 8 + p * 2 + 1];
      }
    }
    out[(size_t)b * 256 + wt] = 1.f / (1.f + expf(-s));
  }
}

extern "C" void kernel_launch(void* const* d_in, const int* in_sizes, int n_in,
                              void* d_out, int out_size, void* d_ws, size_t ws_size,
                              hipStream_t stream) {
  const float* corr = (const float*)d_in[0];
  const float* w1 = (const float*)d_in[1];
  const float* b1 = (const float*)d_in[2];
  const float* w2 = (const float*)d_in[3];
  const float* b2 = (const float*)d_in[4];
  const float* w3 = (const float*)d_in[5];
  const float* b3 = (const float*)d_in[6];
  const float* w4 = (const float*)d_in[7];
  const float* b4 = (const float*)d_in[8];
  const float* w5 = (const float*)d_in[9];
  const float* b5 = (const float*)d_in[10];

  // ws: [0,32M) P khalf slices; [64M,..) B matrices
  float* P = (float*)d_ws;
  unsigned short* Bg1 = (unsigned short*)((char*)d_ws + (64u << 20));
  unsigned short* Bg2 = Bg1 + (size_t)81 * 8 * 4 * 64 * 8;
  unsigned short* Bg3 = Bg2 + (size_t)49 * 2 * 4 * 64 * 8;
  unsigned short* Bg4 = Bg3 + (size_t)25 * 2 * 4 * 64 * 8;

  build_all<<<814, 256, 0, stream>>>(w1, w2, w3, w4, Bg1, Bg2, Bg3, Bg4);
  conv_l1_mfma<<<512, 256, 0, stream>>>(corr, Bg1, P);
  tail_fused<<<256, 512, 0, stream>>>(P, Bg2, Bg3, Bg4, b1, b2, b3, b4, w5, b5,
                                      (float*)d_out);
}